// Round 14
// baseline (617.767 us; speedup 1.0000x reference)
//
#include <hip/hip_runtime.h>

#define NTOK 2048
#define DD   512
#define FFD  2048
#define NE   64
#define KSEL 4
#define NPAIR (NTOK*KSEL)   // 8192
#define BM 96
#define BK 128
#define NT2 192             // static tile-slot upper bound (ceil(8192/96)+63 <= 150)
#define HROWS (NPAIR + 256) // slack for padded A-row reads in gemm_out

typedef short s16x8 __attribute__((ext_vector_type(8)));
typedef float f32x4 __attribute__((ext_vector_type(4)));
typedef float vf4 __attribute__((ext_vector_type(4)));   // clang vector: ok for nontemporal builtins

typedef const __attribute__((address_space(1))) char* gptr_t;
typedef __attribute__((address_space(3))) char* lptr_t;

static __device__ __forceinline__ unsigned short f2bf(float f) {
    unsigned int u = __builtin_bit_cast(unsigned int, f);
    u += 0x7FFFu + ((u >> 16) & 1u);   // RNE
    return (unsigned short)(u >> 16);
}

static __device__ __forceinline__ s16x8 cvt8(vf4 a, vf4 b) {
    s16x8 r;
    r[0] = (short)f2bf(a.x); r[1] = (short)f2bf(a.y);
    r[2] = (short)f2bf(a.z); r[3] = (short)f2bf(a.w);
    r[4] = (short)f2bf(b.x); r[5] = (short)f2bf(b.y);
    r[6] = (short)f2bf(b.z); r[7] = (short)f2bf(b.w);
    return r;
}

// ---------------- K1: LayerNorm (bf16 out) + wave-parallel top-4 routing ----------------
__global__ __launch_bounds__(256) void k_ln_route(
    const float* __restrict__ x, const float* __restrict__ hw,
    const float* __restrict__ gamma, const float* __restrict__ beta,
    unsigned short* __restrict__ xn_bf, int* __restrict__ counts,
    int* __restrict__ tok_e, float* __restrict__ tok_w)
{
    const int t = blockIdx.x;
    const int tid = threadIdx.x;
    const float* xr = x + (size_t)t * DD;
    float v0 = xr[tid];
    float v1 = xr[tid + 256];
    float s = v0 + v1, s2 = v0*v0 + v1*v1;
    #pragma unroll
    for (int off = 32; off > 0; off >>= 1) {
        s  += __shfl_down(s, off);
        s2 += __shfl_down(s2, off);
    }
    __shared__ float rsum[4], rsum2[4];
    __shared__ float smu, srs;
    const int wid = tid >> 6, lane = tid & 63;
    if (lane == 0) { rsum[wid] = s; rsum2[wid] = s2; }
    __syncthreads();
    if (tid == 0) {
        float a = 0.f, b = 0.f;
        for (int i = 0; i < 4; ++i) { a += rsum[i]; b += rsum2[i]; }
        float mu  = a * (1.f / DD);
        float var = b * (1.f / DD) - mu * mu;
        smu = mu; srs = rsqrtf(var + 1e-5f);
    }
    __syncthreads();
    const float mu = smu, rstd = srs;
    xn_bf[(size_t)t*DD + tid]       = f2bf((v0 - mu) * rstd * gamma[tid]       + beta[tid]);
    xn_bf[(size_t)t*DD + tid + 256] = f2bf((v1 - mu) * rstd * gamma[tid + 256] + beta[tid + 256]);

    if (tid < 64) {   // wave 0: butterfly argmax x4
        float v = hw[(size_t)t*NE + tid];
        int   sel[KSEL]; float sw[KSEL];
        #pragma unroll
        for (int j = 0; j < KSEL; ++j) {
            float m = v; int mi = tid;
            #pragma unroll
            for (int off = 32; off > 0; off >>= 1) {
                float ov = __shfl_xor(m, off);
                int   oi = __shfl_xor(mi, off);
                if (ov > m || (ov == m && oi < mi)) { m = ov; mi = oi; }
            }
            if (tid == mi) v = -1e30f;
            sel[j] = mi; sw[j] = m;
        }
        if (tid == 0) {
            float ssum = sw[0] + sw[1] + sw[2] + sw[3];
            float inv = 1.f / (ssum + 1e-8f);
            #pragma unroll
            for (int j = 0; j < KSEL; ++j) {
                tok_e[t*KSEL + j] = sel[j];
                tok_w[t*KSEL + j] = sw[j] * inv;
                atomicAdd(&counts[sel[j]], 1);
            }
        }
    }
}

// ---------------- K2: parallel scan + tile worklist (BM=96) ----------------
__global__ void k_scan(const int* __restrict__ counts, int* __restrict__ offs,
                       int* __restrict__ cursor, int* __restrict__ tile_e,
                       int* __restrict__ tile_r, int* __restrict__ ntiles)
{
    __shared__ int sc[NE], stc[NE];
    const int tid = threadIdx.x;  // 64
    sc[tid] = counts[tid];
    __syncthreads();
    int off = 0;
    for (int i = 0; i < tid; ++i) off += sc[i];
    offs[tid] = off; cursor[tid] = off;
    if (tid == NE-1) offs[NE] = off + sc[NE-1];
    int tc = (sc[tid] + BM - 1) / BM;
    stc[tid] = tc;
    __syncthreads();
    int toff = 0;
    for (int i = 0; i < tid; ++i) toff += stc[i];
    for (int j = 0; j < tc; ++j) { tile_e[toff + j] = tid; tile_r[toff + j] = off + j*BM; }
    if (tid == NE-1) *ntiles = toff + tc;
}

// ---------------- K3: scatter pairs into expert-grouped slots ----------------
__global__ __launch_bounds__(256) void k_scatter(
    const int* __restrict__ tok_e, const float* __restrict__ tok_w,
    int* __restrict__ cursor, int* __restrict__ pair_tok,
    float* __restrict__ pair_w, int* __restrict__ inv)
{
    int i = blockIdx.x * 256 + threadIdx.x;
    if (i >= NPAIR) return;
    int t = i >> 2;
    int e = tok_e[i];
    int slot = atomicAdd(&cursor[e], 1);
    pair_tok[slot] = t;
    pair_w[slot] = tok_w[i];
    inv[i] = slot;
}

// ---------------- K4/K5: bf16 MFMA GEMM — R9 drain-0 schedule, WIDE granule ----------------
// Tile 96x64, BK=128: each W-row visit is 512B contiguous (vs 128B before) -> DRAM
// burst efficiency. 4 waves in 2x2 grid (48 rows x 32 cols each; acc 3x2). LDS:
// As dbuf 48KB + Bs dbuf 32KB = 80KB -> 2 blocks/CU. NK = KD/128 (4 or 16) ->
// 2x fewer barriers than R9. A/B LDS rows are 256B, 16B chunks, chunk ^= row&15.
template<int KD, bool IS_IN, int NYG>
__global__ __launch_bounds__(256, 2) void k_moe_gemm(
    const unsigned short* __restrict__ Abf,
    const float* __restrict__ W, const float* __restrict__ bias,
    const int* __restrict__ tile_e, const int* __restrict__ tile_r,
    const int* __restrict__ ntiles, const int* __restrict__ offs,
    const int* __restrict__ pr_tok, const float* __restrict__ pr_w,
    unsigned short* __restrict__ Hout, float* __restrict__ Pout)
{
    constexpr int NK = KD / BK;
    const int ti = blockIdx.x / NYG;
    if (ti >= *ntiles) return;
    const int e    = tile_e[ti];
    const int row0 = tile_r[ti];
    const int rend = offs[e + 1];
    const int n0   = (blockIdx.x % NYG) * 64;
    const int NOUT = IS_IN ? FFD : DD;

    __shared__ __align__(16) unsigned short As[2 * BM * BK];  // 48 KB dbuf
    __shared__ __align__(16) unsigned short Bs[2 * 64 * BK];  // 32 KB dbuf

    const int tid  = threadIdx.x;
    const int lane = tid & 63, wave = tid >> 6;
    const int lr = lane & 15, lk = lane >> 4;
    const int wmbase = (wave & 1) * 48;    // wave's row-half
    const int wnbase = (wave >> 1) * 32;   // wave's col-half

    // A staging: 6 segs/wave, seg = 4 rows x 256B. lane l -> row seg*4+(l>>4),
    // chunk (l&15)^(row&15) (pre-swizzled source; LDS dest linear).
    const char* asrc[6];
    #pragma unroll
    for (int i = 0; i < 6; ++i) {
        int seg  = wave * 6 + i;
        int r    = seg * 4 + (lane >> 4);
        int cg   = (lane & 15) ^ (r & 15);
        int grow = row0 + r;
        size_t rowbase;
        if (IS_IN) {
            int tok = (grow < rend) ? pr_tok[grow] : pr_tok[row0];
            rowbase = (size_t)tok * (KD * 2);
        } else {
            rowbase = (size_t)grow * (KD * 2);   // HROWS slack covers overshoot
        }
        asrc[i] = (const char*)Abf + rowbase + (size_t)cg * 16;
    }

    // B staging: thread covers W row n0+(tid>>2), 128B contiguous (floats (tid&3)*32..+32)
    const float* wsrc0 = W + (size_t)e * NOUT * KD + (size_t)(n0 + (tid >> 2)) * KD + (tid & 3) * 32;
    const int bn = tid >> 2;           // Bs row 0..63
    const int bc = (tid & 3) * 4;      // first 16B-chunk index this thread writes

    f32x4 acc[3][2];
    #pragma unroll
    for (int m = 0; m < 3; ++m) {
        acc[m][0] = (f32x4){0.f, 0.f, 0.f, 0.f};
        acc[m][1] = (f32x4){0.f, 0.f, 0.f, 0.f};
    }

#define BWRITE(DST, BR)                                                           \
    _Pragma("unroll")                                                             \
    for (int j = 0; j < 4; ++j) {                                                 \
        int c = bc + j;                                                           \
        *(s16x8*)((char*)(DST) + bn * 256 + ((c ^ (bn & 15)) << 4)) =             \
            cvt8(BR[2*j], BR[2*j+1]);                                             \
    }

    // ---- prologue: stage k-tile 0 into buffer 0 ----
    {
        #pragma unroll
        for (int i = 0; i < 6; ++i)
            __builtin_amdgcn_global_load_lds((gptr_t)asrc[i],
                (lptr_t)((char*)As + (wave * 6 + i) * 1024), 16, 0, 0);
        vf4 breg[8];
        #pragma unroll
        for (int j = 0; j < 8; ++j)
            breg[j] = __builtin_nontemporal_load((const vf4*)(wsrc0 + j * 4));
        BWRITE((char*)Bs, breg);
    }
    __syncthreads();

    int buf = 0;
    for (int kt = 0; kt < NK; ++kt) {
        vf4 bregN[8];
        if (kt + 1 < NK) {
            // issue next k-tile stage EARLY: A direct-to-LDS, B to regs (NT hint)
            #pragma unroll
            for (int i = 0; i < 6; ++i)
                __builtin_amdgcn_global_load_lds((gptr_t)(asrc[i] + (size_t)(kt + 1) * (BK * 2)),
                    (lptr_t)((char*)As + (buf ^ 1) * (BM * BK * 2) + (wave * 6 + i) * 1024),
                    16, 0, 0);
            #pragma unroll
            for (int j = 0; j < 8; ++j)
                bregN[j] = __builtin_nontemporal_load(
                    (const vf4*)(wsrc0 + (size_t)(kt + 1) * BK + j * 4));
        }
        __builtin_amdgcn_sched_barrier(0);   // keep load-issue ahead of compute

        {
            const char* Ab = (const char*)As + buf * (BM * BK * 2);
            const char* Bb = (const char*)Bs + buf * (64 * BK * 2);
            #pragma unroll
            for (int h = 0; h < 4; ++h) {
                s16x8 af[3], bfr[2];
                #pragma unroll
                for (int m = 0; m < 3; ++m) {
                    int row = wmbase + m * 16 + lr;
                    af[m] = *(const s16x8*)(Ab + row * 256 + ((((h << 2) | lk) ^ (row & 15)) << 4));
                }
                #pragma unroll
                for (int n = 0; n < 2; ++n) {
                    int row = wnbase + n * 16 + lr;
                    bfr[n] = *(const s16x8*)(Bb + row * 256 + ((((h << 2) | lk) ^ (row & 15)) << 4));
                }
                #pragma unroll
                for (int m = 0; m < 3; ++m) {
                    acc[m][0] = __builtin_amdgcn_mfma_f32_16x16x32_bf16(af[m], bfr[0], acc[m][0], 0, 0, 0);
                    acc[m][1] = __builtin_amdgcn_mfma_f32_16x16x32_bf16(af[m], bfr[1], acc[m][1], 0, 0, 0);
                }
            }
        }
        __builtin_amdgcn_sched_barrier(0);   // don't hoist convert's vmcnt-wait above MFMA

        if (kt + 1 < NK) {
            char* Bw = (char*)Bs + (buf ^ 1) * (64 * BK * 2);
            BWRITE(Bw, bregN);
        }
        __syncthreads();   // drains vmcnt(0): A-lds for next buf + B ds_writes
        buf ^= 1;
    }
#undef BWRITE

    // epilogue: C row = wmbase + m*16 + lk*4 + r, col = n0 + wnbase + n*16 + lr
    #pragma unroll
    for (int m = 0; m < 3; ++m) {
        #pragma unroll
        for (int r = 0; r < 4; ++r) {
            int row = row0 + wmbase + m * 16 + lk * 4 + r;
            if (row < rend) {
                if (IS_IN) {
                    #pragma unroll
                    for (int n = 0; n < 2; ++n) {
                        int f = n0 + wnbase + n * 16 + lr;
                        float v = acc[m][n][r] + bias[e * FFD + f];
                        v = v / (1.f + __expf(-v));
                        Hout[(size_t)row * FFD + f] = f2bf(v);
                    }
                } else {
                    float pw = pr_w[row];
                    #pragma unroll
                    for (int n = 0; n < 2; ++n) {
                        int d = n0 + wnbase + n * 16 + lr;
                        Pout[(size_t)row * DD + d] = (acc[m][n][r] + bias[e * DD + d]) * pw;
                    }
                }
            }
        }
    }
}

// ---------------- K6: per-token combine of 4 expert contributions ----------------
__global__ __launch_bounds__(128) void k_combine(
    const float* __restrict__ pout, const int* __restrict__ inv,
    float* __restrict__ out)
{
    const int t = blockIdx.x;
    const int tid = threadIdx.x;   // 128 threads * float4 = 512 floats
    const float4* p0 = (const float4*)(pout + (size_t)inv[t*4+0]*DD);
    const float4* p1 = (const float4*)(pout + (size_t)inv[t*4+1]*DD);
    const float4* p2 = (const float4*)(pout + (size_t)inv[t*4+2]*DD);
    const float4* p3 = (const float4*)(pout + (size_t)inv[t*4+3]*DD);
    float4 a = p0[tid], b = p1[tid], c = p2[tid], d = p3[tid];
    float4 r;
    r.x = a.x + b.x + c.x + d.x;
    r.y = a.y + b.y + c.y + d.y;
    r.z = a.z + b.z + c.z + d.z;
    r.w = a.w + b.w + c.w + d.w;
    ((float4*)(out + (size_t)t*DD))[tid] = r;
}

extern "C" void kernel_launch(void* const* d_in, const int* in_sizes, int n_in,
                              void* d_out, int out_size, void* d_ws, size_t ws_size,
                              hipStream_t stream)
{
    const float* x     = (const float*)d_in[0];
    const float* hw    = (const float*)d_in[1];
    const float* Win   = (const float*)d_in[2];
    const float* bin   = (const float*)d_in[3];
    const float* Wout  = (const float*)d_in[4];
    const float* bout  = (const float*)d_in[5];
    const float* gamma = (const float*)d_in[6];
    const float* beta  = (const float*)d_in[7];
    float* out = (float*)d_out;

    char* ws = (char*)d_ws;
    size_t o = 0;
    unsigned short* xn_bf = (unsigned short*)(ws + o); o += (size_t)NTOK * DD * 2;    // 2 MB
    unsigned short* H     = (unsigned short*)(ws + o); o += (size_t)HROWS * FFD * 2;  // 34.3 MB
    float* pout   = (float*)(ws + o); o += (size_t)NPAIR * DD * 4;                    // 16 MB
    int*   counts = (int*)(ws + o);   o += 256;
    int*   offs   = (int*)(ws + o);   o += 512;
    int*   cursor = (int*)(ws + o);   o += 256;
    int*   tok_e  = (int*)(ws + o);   o += (size_t)NPAIR * 4;
    float* tok_w  = (float*)(ws + o); o += (size_t)NPAIR * 4;
    int*   inv    = (int*)(ws + o);   o += (size_t)NPAIR * 4;
    int*   pr_tok = (int*)(ws + o);   o += (size_t)NPAIR * 4;
    float* pr_w   = (float*)(ws + o); o += (size_t)NPAIR * 4;
    int*   tile_e = (int*)(ws + o);   o += 1024;
    int*   tile_r = (int*)(ws + o);   o += 1024;
    int*   ntiles = (int*)(ws + o);   o += 256;
    (void)ws_size; (void)in_sizes; (void)n_in; (void)out_size;

    hipMemsetAsync(counts, 0, 256, stream);
    k_ln_route<<<dim3(NTOK), dim3(256), 0, stream>>>(x, hw, gamma, beta, xn_bf, counts, tok_e, tok_w);
    k_scan<<<dim3(1), dim3(64), 0, stream>>>(counts, offs, cursor, tile_e, tile_r, ntiles);
    k_scatter<<<dim3(NPAIR/256), dim3(256), 0, stream>>>(tok_e, tok_w, cursor, pr_tok, pr_w, inv);

    // dense 1-D decode: bid = ti*NYG + yg (live prefix -> even CU fill)
    k_moe_gemm<DD, true, FFD/64><<<dim3(NT2 * (FFD/64)), dim3(256), 0, stream>>>(
        xn_bf, Win, bin, tile_e, tile_r, ntiles, offs, pr_tok, pr_w, H, nullptr);
    k_moe_gemm<FFD, false, DD/64><<<dim3(NT2 * (DD/64)), dim3(256), 0, stream>>>(
        H, Wout, bout, tile_e, tile_r, ntiles, offs, pr_tok, pr_w, nullptr, pout);

    k_combine<<<dim3(NTOK), dim3(128), 0, stream>>>(pout, inv, out);
}

// Round 15
// 231.444 us; speedup vs baseline: 2.6692x; 2.6692x over previous
//
#include <hip/hip_runtime.h>

#define NTOK 2048
#define DD   512
#define FFD  2048
#define NE   64
#define KSEL 4
#define NPAIR (NTOK*KSEL)   // 8192
#define BM 192
#define BK 64
#define NT 128              // static tile-slot upper bound
#define HROWS (NPAIR + 256) // slack for padded A-row reads in gemm_out

typedef short s16x8 __attribute__((ext_vector_type(8)));
typedef float f32x4 __attribute__((ext_vector_type(4)));

typedef const __attribute__((address_space(1))) char* gptr_t;
typedef __attribute__((address_space(3))) char* lptr_t;

static __device__ __forceinline__ unsigned short f2bf(float f) {
    unsigned int u = __builtin_bit_cast(unsigned int, f);
    u += 0x7FFFu + ((u >> 16) & 1u);   // RNE
    return (unsigned short)(u >> 16);
}

// pack float4 -> 4 bf16, swizzled ds_write_b64 into a [n][64] bf16 tile (128B rows)
static __device__ __forceinline__ void packwrite(char* base, int nn, int kb, float4 v) {
    unsigned int lo = (unsigned int)f2bf(v.x) | ((unsigned int)f2bf(v.y) << 16);
    unsigned int hi = (unsigned int)f2bf(v.z) | ((unsigned int)f2bf(v.w) << 16);
    *(uint2*)(base + nn * 128 + (kb ^ ((nn & 7) << 4))) = make_uint2(lo, hi);
}

// ---------------- K1: LayerNorm (bf16 out) + wave-parallel top-4 routing ----------------
__global__ __launch_bounds__(256) void k_ln_route(
    const float* __restrict__ x, const float* __restrict__ hw,
    const float* __restrict__ gamma, const float* __restrict__ beta,
    unsigned short* __restrict__ xn_bf, int* __restrict__ counts,
    int* __restrict__ tok_e, float* __restrict__ tok_w)
{
    const int t = blockIdx.x;
    const int tid = threadIdx.x;
    const float* xr = x + (size_t)t * DD;
    float v0 = xr[tid];
    float v1 = xr[tid + 256];
    float s = v0 + v1, s2 = v0*v0 + v1*v1;
    #pragma unroll
    for (int off = 32; off > 0; off >>= 1) {
        s  += __shfl_down(s, off);
        s2 += __shfl_down(s2, off);
    }
    __shared__ float rsum[4], rsum2[4];
    __shared__ float smu, srs;
    const int wid = tid >> 6, lane = tid & 63;
    if (lane == 0) { rsum[wid] = s; rsum2[wid] = s2; }
    __syncthreads();
    if (tid == 0) {
        float a = 0.f, b = 0.f;
        for (int i = 0; i < 4; ++i) { a += rsum[i]; b += rsum2[i]; }
        float mu  = a * (1.f / DD);
        float var = b * (1.f / DD) - mu * mu;
        smu = mu; srs = rsqrtf(var + 1e-5f);
    }
    __syncthreads();
    const float mu = smu, rstd = srs;
    xn_bf[(size_t)t*DD + tid]       = f2bf((v0 - mu) * rstd * gamma[tid]       + beta[tid]);
    xn_bf[(size_t)t*DD + tid + 256] = f2bf((v1 - mu) * rstd * gamma[tid + 256] + beta[tid + 256]);

    if (tid < 64) {   // wave 0: butterfly argmax x4
        float v = hw[(size_t)t*NE + tid];
        int   sel[KSEL]; float sw[KSEL];
        #pragma unroll
        for (int j = 0; j < KSEL; ++j) {
            float m = v; int mi = tid;
            #pragma unroll
            for (int off = 32; off > 0; off >>= 1) {
                float ov = __shfl_xor(m, off);
                int   oi = __shfl_xor(mi, off);
                if (ov > m || (ov == m && oi < mi)) { m = ov; mi = oi; }
            }
            if (tid == mi) v = -1e30f;
            sel[j] = mi; sw[j] = m;
        }
        if (tid == 0) {
            float ssum = sw[0] + sw[1] + sw[2] + sw[3];
            float inv = 1.f / (ssum + 1e-8f);
            #pragma unroll
            for (int j = 0; j < KSEL; ++j) {
                tok_e[t*KSEL + j] = sel[j];
                tok_w[t*KSEL + j] = sw[j] * inv;
                atomicAdd(&counts[sel[j]], 1);
            }
        }
    }
}

// ---------------- K2: parallel scan + tile worklist ----------------
__global__ void k_scan(const int* __restrict__ counts, int* __restrict__ offs,
                       int* __restrict__ cursor, int* __restrict__ tile_e,
                       int* __restrict__ tile_r, int* __restrict__ ntiles)
{
    __shared__ int sc[NE], stc[NE];
    const int tid = threadIdx.x;  // 64
    sc[tid] = counts[tid];
    __syncthreads();
    int off = 0;
    for (int i = 0; i < tid; ++i) off += sc[i];
    offs[tid] = off; cursor[tid] = off;
    if (tid == NE-1) offs[NE] = off + sc[NE-1];
    int tc = (sc[tid] + BM - 1) / BM;
    stc[tid] = tc;
    __syncthreads();
    int toff = 0;
    for (int i = 0; i < tid; ++i) toff += stc[i];
    for (int j = 0; j < tc; ++j) { tile_e[toff + j] = tid; tile_r[toff + j] = off + j*BM; }
    if (tid == NE-1) *ntiles = toff + tc;
}

// ---------------- K3: scatter pairs into expert-grouped slots ----------------
__global__ __launch_bounds__(256) void k_scatter(
    const int* __restrict__ tok_e, const float* __restrict__ tok_w,
    int* __restrict__ cursor, int* __restrict__ pair_tok,
    float* __restrict__ pair_w, int* __restrict__ inv)
{
    int i = blockIdx.x * 256 + threadIdx.x;
    if (i >= NPAIR) return;
    int t = i >> 2;
    int e = tok_e[i];
    int slot = atomicAdd(&cursor[e], 1);
    pair_tok[slot] = t;
    pair_w[slot] = tok_w[i];
    inv[i] = slot;
}

// ---------------- K4/K5: bf16 MFMA GEMM — R9 structure + XCD-pinned dense decode --------
// bid = (ti>>3)*(8*NYG) + yg*8 + (ti&7): bid%8 == ti%8, so ALL column-blocks of
// a tile land on ONE XCD -> the shared A-gather (gemm_in) and shared H-slice
// (gemm_out: 768KB read by 8 blocks) hit that XCD's L2 instead of being
// re-fetched through L3/HBM per block. Live tiles stay dense & XCD-balanced.
template<int KD, bool IS_IN, int BNX, int NYG>
__global__ __launch_bounds__(256, 2) void k_moe_gemm(
    const unsigned short* __restrict__ Abf,
    const float* __restrict__ W, const float* __restrict__ bias,
    const int* __restrict__ tile_e, const int* __restrict__ tile_r,
    const int* __restrict__ ntiles, const int* __restrict__ offs,
    const int* __restrict__ pr_tok, const float* __restrict__ pr_w,
    unsigned short* __restrict__ Hout, float* __restrict__ Pout)
{
    constexpr int NK = KD / BK;
    constexpr int NB = BNX / 16;       // B float4 loads / thread / k-tile
    constexpr int MT = IS_IN ? 6 : 3;  // m-frags per wave
    const int ti = ((blockIdx.x >> 3) / NYG) * 8 + (blockIdx.x & 7);
    const int yg = (blockIdx.x >> 3) & (NYG - 1);
    if (ti >= *ntiles) return;
    const int e    = tile_e[ti];
    const int row0 = tile_r[ti];
    const int rend = offs[e + 1];
    const int n0   = yg * BNX;
    const int NOUT = IS_IN ? FFD : DD;
    const float* __restrict__ Wb = W + (size_t)e * NOUT * KD;

    __shared__ __align__(16) unsigned short As[2 * BM * BK];   // 48 KB
    __shared__ __align__(16) unsigned short Bs[2 * BNX * BK];  // 32/16 KB

    const int tid  = threadIdx.x;
    const int lane = tid & 63, wave = tid >> 6;
    const int wmbase = IS_IN ? (wave >> 1) * 96 : wave * 48;
    const int wnbase = IS_IN ? (wave & 1) * 64 : 0;

    // A-source per-lane pointers: 6 LDS segments of 1KB per wave (8 rows each).
    // dest (row r, chunk c=lane&7) receives logical chunk c^(r&7) -> swizzled-on-read.
    const char* asrc[6];
    #pragma unroll
    for (int i = 0; i < 6; ++i) {
        int seg  = wave * 6 + i;
        int r    = seg * 8 + (lane >> 3);
        int grow = row0 + r;
        int cg   = (lane & 7) ^ (r & 7);
        size_t rowbase;
        if (IS_IN) {
            int tok = (grow < rend) ? pr_tok[grow] : pr_tok[row0];
            rowbase = (size_t)tok * (KD * 2);
        } else {
            rowbase = (size_t)grow * (KD * 2);   // HROWS slack covers overshoot
        }
        asrc[i] = (const char*)Abf + rowbase + (size_t)cg * 16;
    }

    const float* wsrc0 = Wb + (size_t)(n0 + (tid >> 4)) * KD + (tid & 15) * 4;
    const int nb = tid >> 4;
    const int kb = (tid & 15) * 8;

    f32x4 acc[MT][4];
    #pragma unroll
    for (int m = 0; m < MT; ++m)
        #pragma unroll
        for (int n = 0; n < 4; ++n)
            acc[m][n] = (f32x4){0.f, 0.f, 0.f, 0.f};

    // ---- prologue: stage k-tile 0 into buffer 0 ----
    {
        #pragma unroll
        for (int i = 0; i < 6; ++i)
            __builtin_amdgcn_global_load_lds((gptr_t)asrc[i],
                (lptr_t)((char*)As + (wave * 6 + i) * 1024), 16, 0, 0);
        float4 breg[NB];
        #pragma unroll
        for (int i = 0; i < NB; ++i)
            breg[i] = *(const float4*)(wsrc0 + (size_t)i * 16 * KD);
        #pragma unroll
        for (int i = 0; i < NB; ++i)
            packwrite((char*)Bs, nb + i * 16, kb, breg[i]);
    }
    __syncthreads();

    int buf = 0;
    for (int kt = 0; kt < NK; ++kt) {
        const int k0n = (kt + 1) * BK;
        float4 bregN[NB];
        if (kt + 1 < NK) {
            // issue next k-tile stage EARLY: A direct-to-LDS, B to regs
            #pragma unroll
            for (int i = 0; i < 6; ++i)
                __builtin_amdgcn_global_load_lds((gptr_t)(asrc[i] + (size_t)k0n * 2),
                    (lptr_t)((char*)As + (buf ^ 1) * (BM * BK * 2) + (wave * 6 + i) * 1024),
                    16, 0, 0);
            #pragma unroll
            for (int i = 0; i < NB; ++i)
                bregN[i] = *(const float4*)(wsrc0 + (size_t)i * 16 * KD + k0n);
        }
        __builtin_amdgcn_sched_barrier(0);   // keep load-issue ahead of compute

        const char* Ab = (const char*)As + buf * (BM * BK * 2);
        const char* Bb = (const char*)Bs + buf * (BNX * BK * 2);
        #pragma unroll
        for (int h = 0; h < 2; ++h) {
            s16x8 af[MT], bfr[4];
            const int koff = h * 64 + (lane >> 4) * 16;
            #pragma unroll
            for (int m = 0; m < MT; ++m) {
                int row = wmbase + m * 16 + (lane & 15);
                af[m] = *(const s16x8*)(Ab + row * 128 + (koff ^ ((row & 7) << 4)));
            }
            #pragma unroll
            for (int n = 0; n < 4; ++n) {
                int row = wnbase + n * 16 + (lane & 15);
                bfr[n] = *(const s16x8*)(Bb + row * 128 + (koff ^ ((row & 7) << 4)));
            }
            #pragma unroll
            for (int m = 0; m < MT; ++m)
                #pragma unroll
                for (int n = 0; n < 4; ++n)
                    acc[m][n] = __builtin_amdgcn_mfma_f32_16x16x32_bf16(af[m], bfr[n], acc[m][n], 0, 0, 0);
        }
        __builtin_amdgcn_sched_barrier(0);   // don't hoist convert's vmcnt-wait above MFMA

        if (kt + 1 < NK) {
            char* Bw = (char*)Bs + (buf ^ 1) * (BNX * BK * 2);
            #pragma unroll
            for (int i = 0; i < NB; ++i)
                packwrite(Bw, nb + i * 16, kb, bregN[i]);
        }
        __syncthreads();   // drains vmcnt(0): A-lds for next buf + B ds_writes
        buf ^= 1;
    }

    // epilogue: C row = (lane>>4)*4 + reg, col = lane&15
    #pragma unroll
    for (int m = 0; m < MT; ++m) {
        #pragma unroll
        for (int r = 0; r < 4; ++r) {
            int row = row0 + wmbase + m * 16 + (lane >> 4) * 4 + r;
            if (row < rend) {
                if (IS_IN) {
                    #pragma unroll
                    for (int n = 0; n < 4; ++n) {
                        int f = n0 + wnbase + n * 16 + (lane & 15);
                        float v = acc[m][n][r] + bias[e * FFD + f];
                        v = v / (1.f + __expf(-v));
                        Hout[(size_t)row * FFD + f] = f2bf(v);
                    }
                } else {
                    float pw = pr_w[row];
                    #pragma unroll
                    for (int n = 0; n < 4; ++n) {
                        int d = n0 + wnbase + n * 16 + (lane & 15);
                        Pout[(size_t)row * DD + d] = (acc[m][n][r] + bias[e * DD + d]) * pw;
                    }
                }
            }
        }
    }
}

// ---------------- K6: per-token combine of 4 expert contributions ----------------
__global__ __launch_bounds__(128) void k_combine(
    const float* __restrict__ pout, const int* __restrict__ inv,
    float* __restrict__ out)
{
    const int t = blockIdx.x;
    const int tid = threadIdx.x;   // 128 threads * float4 = 512 floats
    const float4* p0 = (const float4*)(pout + (size_t)inv[t*4+0]*DD);
    const float4* p1 = (const float4*)(pout + (size_t)inv[t*4+1]*DD);
    const float4* p2 = (const float4*)(pout + (size_t)inv[t*4+2]*DD);
    const float4* p3 = (const float4*)(pout + (size_t)inv[t*4+3]*DD);
    float4 a = p0[tid], b = p1[tid], c = p2[tid], d = p3[tid];
    float4 r;
    r.x = a.x + b.x + c.x + d.x;
    r.y = a.y + b.y + c.y + d.y;
    r.z = a.z + b.z + c.z + d.z;
    r.w = a.w + b.w + c.w + d.w;
    ((float4*)(out + (size_t)t*DD))[tid] = r;
}

extern "C" void kernel_launch(void* const* d_in, const int* in_sizes, int n_in,
                              void* d_out, int out_size, void* d_ws, size_t ws_size,
                              hipStream_t stream)
{
    const float* x     = (const float*)d_in[0];
    const float* hw    = (const float*)d_in[1];
    const float* Win   = (const float*)d_in[2];
    const float* bin   = (const float*)d_in[3];
    const float* Wout  = (const float*)d_in[4];
    const float* bout  = (const float*)d_in[5];
    const float* gamma = (const float*)d_in[6];
    const float* beta  = (const float*)d_in[7];
    float* out = (float*)d_out;

    char* ws = (char*)d_ws;
    size_t o = 0;
    unsigned short* xn_bf = (unsigned short*)(ws + o); o += (size_t)NTOK * DD * 2;    // 2 MB
    unsigned short* H     = (unsigned short*)(ws + o); o += (size_t)HROWS * FFD * 2;  // 34.3 MB
    float* pout   = (float*)(ws + o); o += (size_t)NPAIR * DD * 4;                    // 16 MB
    int*   counts = (int*)(ws + o);   o += 256;
    int*   offs   = (int*)(ws + o);   o += 512;
    int*   cursor = (int*)(ws + o);   o += 256;
    int*   tok_e  = (int*)(ws + o);   o += (size_t)NPAIR * 4;
    float* tok_w  = (float*)(ws + o); o += (size_t)NPAIR * 4;
    int*   inv    = (int*)(ws + o);   o += (size_t)NPAIR * 4;
    int*   pr_tok = (int*)(ws + o);   o += (size_t)NPAIR * 4;
    float* pr_w   = (float*)(ws + o); o += (size_t)NPAIR * 4;
    int*   tile_e = (int*)(ws + o);   o += 512;
    int*   tile_r = (int*)(ws + o);   o += 512;
    int*   ntiles = (int*)(ws + o);   o += 256;
    (void)ws_size; (void)in_sizes; (void)n_in; (void)out_size;

    hipMemsetAsync(counts, 0, 256, stream);
    k_ln_route<<<dim3(NTOK), dim3(256), 0, stream>>>(x, hw, gamma, beta, xn_bf, counts, tok_e, tok_w);
    k_scan<<<dim3(1), dim3(64), 0, stream>>>(counts, offs, cursor, tile_e, tile_r, ntiles);
    k_scatter<<<dim3(NPAIR/256), dim3(256), 0, stream>>>(tok_e, tok_w, cursor, pr_tok, pr_w, inv);

    // XCD-pinned dense decode: bid%8 == ti%8 (all column-blocks of a tile share an XCD)
    k_moe_gemm<DD, true, 128, FFD/128><<<dim3(NT * (FFD/128)), dim3(256), 0, stream>>>(
        xn_bf, Win, bin, tile_e, tile_r, ntiles, offs, pr_tok, pr_w, H, nullptr);
    k_moe_gemm<FFD, false, 64, DD/64><<<dim3(NT * (DD/64)), dim3(256), 0, stream>>>(
        H, Wout, bout, tile_e, tile_r, ntiles, offs, pr_tok, pr_w, nullptr, pout);

    k_combine<<<dim3(NTOK), dim3(128), 0, stream>>>(pout, inv, out);
}